// Round 12
// baseline (70.033 us; speedup 1.0000x reference)
//
#include <hip/hip_runtime.h>

// TokenEmbedding_51153060495497
// x: (256, 512, 7) f32;  kernels: (74, 8, 3) f32; keff = kernels[:,:,1]
// out flat: (256*513, 512) f32
//   row r = b*513 + t;  f in [0,512):
//     f < 511 : c = f/73, k = f%73
//     f == 511: c = 0,    k = 73
//   out[r*512+f] = sum_j xp[b, t+j-4, c] * keff[k, j]  (xp zero outside [0,512))
//
// r8 structure (best: 55.9 us): pair/thread, scalar sliding window from LDS,
// 64-row chunks, vectorized prologue, dense 8B stores, 8 waves/SIMD.
// This round: fuse the t=512 tail row into chunk 7 (its zero-padded LDS
// window already holds all taps) -> grid 8x256 = 2048 blocks, exactly
// 8 blocks/CU, no ragged 9th dispatch round, no tiny tail blocks.

typedef float v2f __attribute__((ext_vector_type(2)));
typedef float v4f __attribute__((ext_vector_type(4)));

#define CDIM 7
#define TROWS 513
#define CHUNK 64
#define WIN_ROWS 72                    // CHUNK + 8
#define WIN_ELEMS (WIN_ROWS * CDIM)    // 504 floats = 126 float4

__device__ __forceinline__ int chan_of(int f) { return (f == 511) ? 0 : (f / 73); }
__device__ __forceinline__ int kidx_of(int f) { return (f == 511) ? 73 : (f % 73); }

__global__ __launch_bounds__(256, 8) void tok_conv_kernel(
    const float* __restrict__ x,     // (256,512,7)
    const float* __restrict__ kern,  // (74,8,3)
    float* __restrict__ out)         // (131328, 512)
{
  __shared__ __align__(16) float lds[WIN_ELEMS];

  const int tid   = threadIdx.x;     // pair index 0..255
  const int b     = blockIdx.y;
  const int chunk = blockIdx.x;      // 0..7
  const float* xb = x + b * (512 * CDIM);

  const int f0 = 2 * tid, f1 = f0 + 1;
  const int c0 = chan_of(f0), k0 = kidx_of(f0);
  const int c1 = chan_of(f1), k1 = kidx_of(f1);

  // packed weights: kp[j] = (keff[k0][j], keff[k1][j]) — no zero slots
  v2f kp[8];
#pragma unroll
  for (int j = 0; j < 8; ++j)
    kp[j] = (v2f){kern[k0 * 24 + j * 3 + 1], kern[k1 * 24 + j * 3 + 1]};

  const int t0 = chunk * CHUNK;

  // ---- stage rows t0-4 .. t0+67 (x7 ch) into LDS ----
  if (chunk >= 1 && chunk <= 6) {
    // interior: no padding needed; (t0-4)*7 floats offset is 16B-aligned
    const v4f* src = reinterpret_cast<const v4f*>(xb + (t0 - 4) * CDIM);
    if (tid < WIN_ELEMS / 4)
      reinterpret_cast<v4f*>(lds)[tid] = src[tid];
  } else {
    // edge chunks (0 and 7): scalar with zero-padding
#pragma unroll
    for (int i = tid; i < WIN_ELEMS; i += 256) {
      const int r = i / CDIM;
      const int c = i - r * CDIM;
      const int p = t0 - 4 + r;
      lds[i] = ((unsigned)p < 512u) ? xb[p * CDIM + c] : 0.f;
    }
  }
  __syncthreads();

  // tap j of step s lives at lds[(s+j)*7 + c]
  int bx0 = c0, bx1 = c1;

  // initial window (step 0, taps 0..7)
  v2f w[8];
#pragma unroll
  for (int j = 0; j < 8; ++j)
    w[j] = (v2f){lds[bx0 + j * CDIM], lds[bx1 + j * CDIM]};

  v2f* orow = reinterpret_cast<v2f*>(out + ((size_t)b * TROWS + t0) * 512) + tid;

#pragma unroll 1
  for (int g = 0; g < 8; ++g) {        // 8 groups x 8 steps = 64 rows
#pragma unroll
    for (int u = 0; u < 8; ++u) {
      // prefetch next row's taps (immediate LDS offsets from bx)
      v2f nv;
      nv.x = lds[bx0 + (u + 8) * CDIM];
      nv.y = lds[bx1 + (u + 8) * CDIM];

      v2f acc = {0.f, 0.f};
#pragma unroll
      for (int j = 0; j < 8; ++j)
        acc += w[(u + j) & 7] * kp[j];   // v_pk_fma_f32, both slots useful

      *orow = acc;                        // dense 8B store, 512B/wave
      orow += 256;                        // next row (512 floats)

      w[u & 7] = nv;                      // slide window by one row
    }
    bx0 += 8 * CDIM;
    bx1 += 8 * CDIM;
  }

  // ---- fused tail: chunk 7 computes row t=512 from its own LDS window ----
  // After the loop bx0/bx1 point at window row 64 (= p 508); rows 68..71
  // are the zero padding, so the plain 8-tap dot gives the correct result.
  if (chunk == 7) {
    v2f acc = {0.f, 0.f};
#pragma unroll
    for (int j = 0; j < 8; ++j) {
      const v2f wv = {lds[bx0 + j * CDIM], lds[bx1 + j * CDIM]};
      acc += wv * kp[j];
    }
    *orow = acc;                          // row 512 (orow advanced 64 rows)
  }
}

extern "C" void kernel_launch(void* const* d_in, const int* in_sizes, int n_in,
                              void* d_out, int out_size, void* d_ws, size_t ws_size,
                              hipStream_t stream) {
  const float* x    = (const float*)d_in[0];
  const float* kern = (const float*)d_in[1];
  float* out        = (float*)d_out;

  dim3 grid(8, 256);   // 2048 blocks: 64-row chunks; chunk 7 fuses row 512
  tok_conv_kernel<<<grid, 256, 0, stream>>>(x, kern, out);
}

// Round 13
// 69.592 us; speedup vs baseline: 1.0063x; 1.0063x over previous
//
#include <hip/hip_runtime.h>

// TokenEmbedding_51153060495497
// x: (256, 512, 7) f32;  kernels: (74, 8, 3) f32; keff = kernels[:,:,1]
// out flat: (256*513, 512) f32
//   row r = b*513 + t;  f in [0,512):
//     f < 511 : c = f/73, k = f%73
//     f == 511: c = 0,    k = 73
//   out[r*512+f] = sum_j xp[b, t+j-4, c] * keff[k, j]  (xp zero outside [0,512))
//
// r12 body + grid transpose: blockIdx.x = batch, blockIdx.y = chunk, so the
// XCD round-robin (linear id mod 8 = batch mod 8) decorrelates from chunk
// type and every XCD gets the same edge/interior block mix. (r12's grid(8,256)
// put all expensive edge chunks on XCDs 0 and 7 -> +14us imbalance.)

typedef float v2f __attribute__((ext_vector_type(2)));
typedef float v4f __attribute__((ext_vector_type(4)));

#define CDIM 7
#define TROWS 513
#define CHUNK 64
#define WIN_ROWS 72                    // CHUNK + 8
#define WIN_ELEMS (WIN_ROWS * CDIM)    // 504 floats = 126 float4

__device__ __forceinline__ int chan_of(int f) { return (f == 511) ? 0 : (f / 73); }
__device__ __forceinline__ int kidx_of(int f) { return (f == 511) ? 73 : (f % 73); }

__global__ __launch_bounds__(256, 8) void tok_conv_kernel(
    const float* __restrict__ x,     // (256,512,7)
    const float* __restrict__ kern,  // (74,8,3)
    float* __restrict__ out)         // (131328, 512)
{
  __shared__ __align__(16) float lds[WIN_ELEMS];

  const int tid   = threadIdx.x;     // pair index 0..255
  const int b     = blockIdx.x;      // batch  (fast-varying -> XCD = b & 7)
  const int chunk = blockIdx.y;      // 0..7
  const float* xb = x + b * (512 * CDIM);

  const int f0 = 2 * tid, f1 = f0 + 1;
  const int c0 = chan_of(f0), k0 = kidx_of(f0);
  const int c1 = chan_of(f1), k1 = kidx_of(f1);

  // packed weights: kp[j] = (keff[k0][j], keff[k1][j]) — no zero slots
  v2f kp[8];
#pragma unroll
  for (int j = 0; j < 8; ++j)
    kp[j] = (v2f){kern[k0 * 24 + j * 3 + 1], kern[k1 * 24 + j * 3 + 1]};

  const int t0 = chunk * CHUNK;

  // ---- stage rows t0-4 .. t0+67 (x7 ch) into LDS ----
  if (chunk >= 1 && chunk <= 6) {
    // interior: no padding needed; (t0-4)*7 floats offset is 16B-aligned
    const v4f* src = reinterpret_cast<const v4f*>(xb + (t0 - 4) * CDIM);
    if (tid < WIN_ELEMS / 4)
      reinterpret_cast<v4f*>(lds)[tid] = src[tid];
  } else {
    // edge chunks (0 and 7): scalar with zero-padding
#pragma unroll
    for (int i = tid; i < WIN_ELEMS; i += 256) {
      const int r = i / CDIM;
      const int c = i - r * CDIM;
      const int p = t0 - 4 + r;
      lds[i] = ((unsigned)p < 512u) ? xb[p * CDIM + c] : 0.f;
    }
  }
  __syncthreads();

  // tap j of step s lives at lds[(s+j)*7 + c]
  int bx0 = c0, bx1 = c1;

  // initial window (step 0, taps 0..7)
  v2f w[8];
#pragma unroll
  for (int j = 0; j < 8; ++j)
    w[j] = (v2f){lds[bx0 + j * CDIM], lds[bx1 + j * CDIM]};

  v2f* orow = reinterpret_cast<v2f*>(out + ((size_t)b * TROWS + t0) * 512) + tid;

#pragma unroll 1
  for (int g = 0; g < 8; ++g) {        // 8 groups x 8 steps = 64 rows
#pragma unroll
    for (int u = 0; u < 8; ++u) {
      // prefetch next row's taps (immediate LDS offsets from bx)
      v2f nv;
      nv.x = lds[bx0 + (u + 8) * CDIM];
      nv.y = lds[bx1 + (u + 8) * CDIM];

      v2f acc = {0.f, 0.f};
#pragma unroll
      for (int j = 0; j < 8; ++j)
        acc += w[(u + j) & 7] * kp[j];   // v_pk_fma_f32, both slots useful

      *orow = acc;                        // dense 8B store, 512B/wave
      orow += 256;                        // next row (512 floats)

      w[u & 7] = nv;                      // slide window by one row
    }
    bx0 += 8 * CDIM;
    bx1 += 8 * CDIM;
  }

  // ---- fused tail: chunk 7 computes row t=512 from its own LDS window ----
  // After the loop bx0/bx1 point at window row 64 (= p 508); rows 68..71
  // are the zero padding, so the plain 8-tap dot gives the correct result.
  if (chunk == 7) {
    v2f acc = {0.f, 0.f};
#pragma unroll
    for (int j = 0; j < 8; ++j) {
      const v2f wv = {lds[bx0 + j * CDIM], lds[bx1 + j * CDIM]};
      acc += wv * kp[j];
    }
    *orow = acc;                          // row 512 (orow advanced 64 rows)
  }
}

extern "C" void kernel_launch(void* const* d_in, const int* in_sizes, int n_in,
                              void* d_out, int out_size, void* d_ws, size_t ws_size,
                              hipStream_t stream) {
  const float* x    = (const float*)d_in[0];
  const float* kern = (const float*)d_in[1];
  float* out        = (float*)d_out;

  dim3 grid(256, 8);   // x = batch (XCD round-robin), y = chunk
  tok_conv_kernel<<<grid, 256, 0, stream>>>(x, kern, out);
}

// Round 14
// 55.316 us; speedup vs baseline: 1.2660x; 1.2581x over previous
//
#include <hip/hip_runtime.h>

// TokenEmbedding_51153060495497
// x: (256, 512, 7) f32;  kernels: (74, 8, 3) f32; keff = kernels[:,:,1]
// out flat: (256*513, 512) f32
//   row r = b*513 + t;  f in [0,512):
//     f < 511 : c = f/73, k = f%73
//     f == 511: c = 0,    k = 73
//   out[r*512+f] = sum_j xp[b, t+j-4, c] * keff[k, j]  (xp zero outside [0,512))
//
// CHAMPION (r8, 55.9 us) — exact revert. Pair version, 64-row chunks: each
// thread owns ONE feature pair (f=2p,2p+1), walks 64 rows via a scalar
// sliding window from LDS. Vectorized prologue for interior chunks. Dense
// 8B stores. ~50 VGPR -> 8 waves/SIMD. Separate trivial tail blocks
// (chunk 8) for the t=512 row; grid 9x256 staggers block generations.

typedef float v2f __attribute__((ext_vector_type(2)));
typedef float v4f __attribute__((ext_vector_type(4)));

#define CDIM 7
#define TROWS 513
#define CHUNK 64
#define WIN_ROWS 72                    // CHUNK + 8
#define WIN_ELEMS (WIN_ROWS * CDIM)    // 504 floats = 126 float4

__device__ __forceinline__ int chan_of(int f) { return (f == 511) ? 0 : (f / 73); }
__device__ __forceinline__ int kidx_of(int f) { return (f == 511) ? 73 : (f % 73); }

__global__ __launch_bounds__(256, 8) void tok_conv_kernel(
    const float* __restrict__ x,     // (256,512,7)
    const float* __restrict__ kern,  // (74,8,3)
    float* __restrict__ out)         // (131328, 512)
{
  __shared__ __align__(16) float lds[WIN_ELEMS];

  const int tid   = threadIdx.x;     // pair index 0..255
  const int b     = blockIdx.y;
  const int chunk = blockIdx.x;      // 0..8
  const float* xb = x + b * (512 * CDIM);

  const int f0 = 2 * tid, f1 = f0 + 1;
  const int c0 = chan_of(f0), k0 = kidx_of(f0);
  const int c1 = chan_of(f1), k1 = kidx_of(f1);

  // packed weights: kp[j] = (keff[k0][j], keff[k1][j]) — no zero slots
  v2f kp[8];
#pragma unroll
  for (int j = 0; j < 8; ++j)
    kp[j] = (v2f){kern[k0 * 24 + j * 3 + 1], kern[k1 * 24 + j * 3 + 1]};

  // ---- tail chunk: the single t=512 row ----
  if (chunk == 8) {
    v2f acc = {0.f, 0.f};
#pragma unroll
    for (int j = 0; j < 8; ++j) {
      const int p   = 508 + j;          // t=512: taps p = 508..515
      const bool ok = p < 512;
      const int bse = (ok ? p : 0) * CDIM;
      v2f w;
      w.x = ok ? xb[bse + c0] : 0.f;
      w.y = ok ? xb[bse + c1] : 0.f;
      acc += w * kp[j];
    }
    reinterpret_cast<v2f*>(out + ((size_t)b * TROWS + 512) * 512)[tid] = acc;
    return;
  }

  const int t0 = chunk * CHUNK;

  // ---- stage rows t0-4 .. t0+67 (x7 ch) into LDS ----
  if (chunk >= 1 && chunk <= 6) {
    // interior: no padding needed; (t0-4)*7 floats offset is 16B-aligned
    const v4f* src = reinterpret_cast<const v4f*>(xb + (t0 - 4) * CDIM);
    if (tid < WIN_ELEMS / 4)
      reinterpret_cast<v4f*>(lds)[tid] = src[tid];
  } else {
    // edge chunks: scalar with zero-padding
#pragma unroll
    for (int i = tid; i < WIN_ELEMS; i += 256) {
      const int r = i / CDIM;
      const int c = i - r * CDIM;
      const int p = t0 - 4 + r;
      lds[i] = ((unsigned)p < 512u) ? xb[p * CDIM + c] : 0.f;
    }
  }
  __syncthreads();

  // tap j of step s lives at lds[(s+j)*7 + c]
  int bx0 = c0, bx1 = c1;

  // initial window (step 0, taps 0..7)
  v2f w[8];
#pragma unroll
  for (int j = 0; j < 8; ++j)
    w[j] = (v2f){lds[bx0 + j * CDIM], lds[bx1 + j * CDIM]};

  v2f* orow = reinterpret_cast<v2f*>(out + ((size_t)b * TROWS + t0) * 512) + tid;

#pragma unroll 1
  for (int g = 0; g < 8; ++g) {        // 8 groups x 8 steps = 64 rows
#pragma unroll
    for (int u = 0; u < 8; ++u) {
      // prefetch next row's taps (immediate LDS offsets from bx)
      v2f nv;
      nv.x = lds[bx0 + (u + 8) * CDIM];
      nv.y = lds[bx1 + (u + 8) * CDIM];

      v2f acc = {0.f, 0.f};
#pragma unroll
      for (int j = 0; j < 8; ++j)
        acc += w[(u + j) & 7] * kp[j];   // v_pk_fma_f32, both slots useful

      *orow = acc;                        // dense 8B store, 512B/wave
      orow += 256;                        // next row (512 floats)

      w[u & 7] = nv;                      // slide window by one row
    }
    bx0 += 8 * CDIM;
    bx1 += 8 * CDIM;
  }
}

extern "C" void kernel_launch(void* const* d_in, const int* in_sizes, int n_in,
                              void* d_out, int out_size, void* d_ws, size_t ws_size,
                              hipStream_t stream) {
  const float* x    = (const float*)d_in[0];
  const float* kern = (const float*)d_in[1];
  float* out        = (float*)d_out;

  dim3 grid(9, 256);   // chunks 0..7: 64-row stream; chunk 8: t=512 row
  tok_conv_kernel<<<grid, 256, 0, stream>>>(x, kern, out);
}